// Round 6
// baseline (905.118 us; speedup 1.0000x reference)
//
#include <hip/hip_runtime.h>
#include <hip/hip_bf16.h>

// ScaledDotProductAttention: B=2,H=16,S=2048,D=64 -> (output[B,H,S,D], weights[B,H,S,S]).
// Inputs float32, outputs FLOAT32. Two-pass flash-with-weights, bf16 MFMA, swapped operands.
// R8:
//  - PV via mfma 16x16x16: B-frag (W^T) = the 4 w-values each lane just computed in the
//    QK^T C-frag -> W never touches LDS (removes Wts writes/reads + their bank conflicts).
//  - Mask: direct per-lane global loads (4B x 4/chunk, L2-resident, issued a phase early).
//    Removes Msk LDS entirely.
//  - Freed LDS -> full K+V double-buffer (36864 B, 4 blocks/CU), 1 raw barrier per chunk
//    in BOTH passes (lgkmcnt-only barrier; global loads/stores stay in flight).
//  - Plain stores everywhere (nt stores amplified WRITE 557->705 MB and poison vmcnt FIFO).

namespace {

constexpr int kS = 2048;
constexpr int kD = 64;
constexpr int kBH = 32;            // B*H
constexpr int kTQW = 16;           // q rows per wave
constexpr int kNW = 4;             // waves per block
constexpr int kTQB = kTQW * kNW;   // 64 q rows per block
constexpr int kChunk = 64;         // k rows per chunk
constexpr int kNC = kS / kChunk;   // 32 chunks
constexpr int kNB = kBH * (kS / kTQB);           // 1024 blocks
constexpr size_t kWOff = (size_t)kBH * kS * kD;  // weights offset in d_out

typedef __attribute__((ext_vector_type(8))) short bf16x8;
typedef __attribute__((ext_vector_type(4))) short bf16x4;
typedef __attribute__((ext_vector_type(4))) float f32x4;

__device__ inline short f2bf(float f) {
  union { float f; unsigned u; } x; x.f = f;
  return (short)((x.u + 0x7fffu + ((x.u >> 16) & 1u)) >> 16);  // RNE
}

__device__ inline unsigned pk2bf(float a, float b) {
  return (unsigned)(unsigned short)f2bf(a) | ((unsigned)(unsigned short)f2bf(b) << 16);
}

__device__ inline bf16x8 cvt8(float4 a, float4 b, float scale) {
  bf16x8 f;
  f[0] = f2bf(a.x * scale); f[1] = f2bf(a.y * scale);
  f[2] = f2bf(a.z * scale); f[3] = f2bf(a.w * scale);
  f[4] = f2bf(b.x * scale); f[5] = f2bf(b.y * scale);
  f[6] = f2bf(b.z * scale); f[7] = f2bf(b.w * scale);
  return f;
}

__device__ inline f32x4 mfma32(bf16x8 a, bf16x8 b, f32x4 c) {
  return __builtin_amdgcn_mfma_f32_16x16x32_bf16(a, b, c, 0, 0, 0);
}

// 16x16x16 bf16 MFMA: builtin name differs across ROCm generations; chain with asm fallback.
__device__ inline f32x4 mfma16(bf16x4 a, bf16x4 b, f32x4 c) {
#if __has_builtin(__builtin_amdgcn_mfma_f32_16x16x16bf16_1k)
  return __builtin_amdgcn_mfma_f32_16x16x16bf16_1k(a, b, c, 0, 0, 0);
#elif __has_builtin(__builtin_amdgcn_mfma_f32_16x16x16_bf16)
  return __builtin_amdgcn_mfma_f32_16x16x16_bf16(a, b, c, 0, 0, 0);
#else
  f32x4 d = c;
  asm volatile("v_mfma_f32_16x16x16_bf16 %0, %1, %2, %0" : "+v"(d) : "v"(a), "v"(b));
  return d;
#endif
}

// Barrier that does NOT drain vmcnt: LDS writes made visible (lgkmcnt(0)); in-flight
// global loads/stores survive. "memory" clobbers pin compiler ordering.
__device__ inline void block_sync_lds() {
  asm volatile("s_waitcnt lgkmcnt(0)" ::: "memory");
  __builtin_amdgcn_s_barrier();
  asm volatile("" ::: "memory");
}

__global__ __launch_bounds__(256, 4) void attn_fused(
    const float* __restrict__ qg, const float* __restrict__ kg,
    const float* __restrict__ vg, const unsigned int* __restrict__ mg,
    float* __restrict__ outg) {
  // 36864 B: K0,K1 (K chunk dbuf) + V0,V1 (V^T chunk dbuf), each [64][72] bf16.
  __shared__ __align__(16) short SH[18432];
  short (*K0)[72] = (short(*)[72])(SH);
  short (*K1)[72] = (short(*)[72])(SH + 4608);
  short (*V0)[72] = (short(*)[72])(SH + 9216);
  short (*V1)[72] = (short(*)[72])(SH + 13824);

  const int tid  = threadIdx.x;
  const int wv   = tid >> 6;
  const int lane = tid & 63;
  const int l15  = lane & 15;
  const int quad = lane >> 4;

  // XCD-chunked bijective swizzle (1024 % 8 == 0): same-bh blocks share one XCD's L2.
  const int bid  = blockIdx.x;
  const int work = ((bid & 7) << 7) | (bid >> 3);
  const int qt   = work & 31;
  const int bh   = work >> 5;
  const int b    = bh >> 4;          // H = 16
  const int q0b  = qt * kTQB;

  // ---- mask encoding detection (uint8 | int32 | float32 | bf16), element test != 0 ----
  int allW32 = 1, allI32 = 1, allBF = 1;
#pragma unroll
  for (int i = 0; i < 64; ++i) {
    const unsigned u = mg[i];
    const unsigned lo = u & 0xFFFFu, hi = u >> 16;
    allW32 &= (int)(u == 0u || u == 0x3F800000u);
    allI32 &= (int)(u == 0u || u == 1u);
    allBF  &= (int)((lo == 0u || lo == 0x3F80u) && (hi == 0u || hi == 0x3F80u));
  }
  int msz;
  if (allI32)      msz = 4;
  else if (allW32) msz = 4;
  else if (allBF)  msz = 2;
  else             msz = 1;
  const unsigned char* mB = (const unsigned char*)mg + (size_t)b * kS * kS * msz;

  const float* qbase = qg + (size_t)bh * kS * kD;
  const float* kbase = kg + (size_t)bh * kS * kD;
  const float* vbase = vg + (size_t)bh * kS * kD;
  float* obase = outg + (size_t)bh * kS * kD;
  float* wbase = outg + kWOff + (size_t)bh * kS * kS;

  const int qrow = q0b + wv * kTQW + l15;   // row-per-lane (swapped layout)

  // ---- Q fragments (B-operand of swapped QK^T), pre-scaled by 1/8, in registers ----
  bf16x8 aq[2];
#pragma unroll
  for (int dh = 0; dh < 2; ++dh) {
    const float* p = qbase + (size_t)qrow * kD + dh * 32 + quad * 8;
    aq[dh] = cvt8(*(const float4*)p, *(const float4*)(p + 4), 0.125f);
  }

  // ---- staging thread maps ----
  const int si = tid >> 2;          // K row 0..63
  const int sj = (tid & 3) << 4;    // K col segment 0/16/32/48
  const int vd = (tid & 7) << 3;    // V: d base
  const int vk = (tid >> 3) << 1;   // V: even krel pair base
  float4 rk[4], rv[4];

  auto k_issue = [&](int c) {
    const float* p = kbase + (size_t)(c * kChunk + si) * kD + sj;
    rk[0] = *(const float4*)p;       rk[1] = *(const float4*)(p + 4);
    rk[2] = *(const float4*)(p + 8); rk[3] = *(const float4*)(p + 12);
  };
  auto k_write = [&](short (*Kdst)[72]) {
    *(bf16x8*)&Kdst[si][sj]     = cvt8(rk[0], rk[1], 1.0f);
    *(bf16x8*)&Kdst[si][sj + 8] = cvt8(rk[2], rk[3], 1.0f);
  };

  auto v_issue = [&](int c) {
    const float* p = vbase + (size_t)(c * kChunk + vk) * kD + vd;
    rv[0] = *(const float4*)p;        rv[1] = *(const float4*)(p + 4);
    rv[2] = *(const float4*)(p + kD); rv[3] = *(const float4*)(p + kD + 4);
  };
  // V^T: pair (vk,vk+1) packed per dword; pair index XOR-swizzled by d-group.
  auto v_write = [&](short (*Vdst)[72]) {
    const float* lo = (const float*)&rv[0];
    const float* hi = (const float*)&rv[2];
#pragma unroll
    for (int d = 0; d < 8; ++d) {
      const int dd = vd + d;
      const int ps = (vk >> 1) ^ (((dd >> 3) & 7) << 2);
      *(unsigned*)&Vdst[dd][2 * ps] = pk2bf(lo[d], hi[d]);
    }
  };

  // ---- per-lane direct mask loads: this lane's 16 bytes per chunk (own row/cols) ----
  uint4 mr[4];       // raw per tile (unrolled static indexing only)
  unsigned mu[4];    // byte-encoded: byte r != 0 <=> masked
  auto m_issue = [&](int c) {
    const int col0 = c * kChunk + quad * 4;
#pragma unroll
    for (int t = 0; t < 4; ++t) {
      const size_t e = (size_t)qrow * kS + col0 + t * 16;
      if (msz == 1)      mr[t].x = *(const unsigned*)(mB + e);
      else if (msz == 4) mr[t]   = *(const uint4*)((const unsigned*)mB + e);
      else {
        const unsigned* p = (const unsigned*)((const unsigned short*)mB + e);
        mr[t].x = p[0]; mr[t].y = p[1];
      }
    }
  };
  auto m_conv = [&]() {
#pragma unroll
    for (int t = 0; t < 4; ++t) {
      if (msz == 1)      mu[t] = mr[t].x;
      else if (msz == 4) mu[t] = (mr[t].x ? 1u : 0u) | ((mr[t].y ? 1u : 0u) << 8) |
                                 ((mr[t].z ? 1u : 0u) << 16) | ((mr[t].w ? 1u : 0u) << 24);
      else {
        const unsigned a = mr[t].x, bb = mr[t].y;
        mu[t] = ((a & 0xFFFFu) ? 1u : 0u) | (((a >> 16) ? 1u : 0u) << 8) |
                (((bb & 0xFFFFu) ? 1u : 0u) << 16) | (((bb >> 16) ? 1u : 0u) << 24);
      }
    }
  };

  // ================= Pass A: l = sum_k exp(s); 1 barrier/chunk, K dbuf =================
  float lsum = 0.f;
  k_issue(0); k_write(K0); k_issue(1);
  block_sync_lds();
  for (int c = 0; c < kNC; ++c) {
    m_issue(c);
    if (c + 1 < kNC) k_write((c & 1) ? K0 : K1);
    if (c + 2 < kNC) k_issue(c + 2);
    m_conv();
    short (*K)[72] = (c & 1) ? K1 : K0;
#pragma unroll
    for (int t = 0; t < 4; ++t) {
      bf16x8 f0 = *(const bf16x8*)&K[t * 16 + l15][quad * 8];
      bf16x8 f1 = *(const bf16x8*)&K[t * 16 + l15][32 + quad * 8];
      f32x4 acc = {0.f, 0.f, 0.f, 0.f};
      acc = mfma32(f0, aq[0], acc);
      acc = mfma32(f1, aq[1], acc);
      // S^T tile: lane holds S[q=l15][k = t*16 + quad*4 + r]
#pragma unroll
      for (int r = 0; r < 4; ++r) {
        const float e = __expf(acc[r]);
        lsum += ((mu[t] >> (8 * r)) & 0xFFu) ? 1.0f : e;   // masked -> exp(-1e-9) == 1.0f
      }
    }
    block_sync_lds();
  }

  // reduce across the 4 quads holding this q row's column subsets
  lsum += __shfl_xor(lsum, 16);
  lsum += __shfl_xor(lsum, 32);
  const float inv = 1.0f / lsum;

  // ================= Pass B: weights (plain f32x4) + PV; 1 barrier/chunk ===============
  f32x4 acco[4];
#pragma unroll
  for (int d = 0; d < 4; ++d) acco[d] = (f32x4){0.f, 0.f, 0.f, 0.f};

  k_issue(0); v_issue(0);
  k_write(K0); v_write(V0);
  k_issue(1); v_issue(1);
  block_sync_lds();
  float* const wrow = wbase + (size_t)qrow * kS;
  for (int c = 0; c < kNC; ++c) {
    m_issue(c);
    if (c + 1 < kNC) { k_write((c & 1) ? K0 : K1); v_write((c & 1) ? V0 : V1); }
    if (c + 2 < kNC) { k_issue(c + 2); v_issue(c + 2); }
    m_conv();
    short (*K)[72] = (c & 1) ? K1 : K0;
    short (*V)[72] = (c & 1) ? V1 : V0;
    __builtin_amdgcn_s_setprio(1);
#pragma unroll
    for (int t = 0; t < 4; ++t) {
      bf16x8 f0 = *(const bf16x8*)&K[t * 16 + l15][quad * 8];
      bf16x8 f1 = *(const bf16x8*)&K[t * 16 + l15][32 + quad * 8];
      f32x4 acc = {0.f, 0.f, 0.f, 0.f};
      acc = mfma32(f0, aq[0], acc);
      acc = mfma32(f1, aq[1], acc);
      const unsigned m = mu[t];
      const float w0 = ((m       & 0xFFu) ? 1.0f : __expf(acc[0])) * inv;
      const float w1 = ((m >> 8  & 0xFFu) ? 1.0f : __expf(acc[1])) * inv;
      const float w2 = ((m >> 16 & 0xFFu) ? 1.0f : __expf(acc[2])) * inv;
      const float w3 = ((m >> 24        ) ? 1.0f : __expf(acc[3])) * inv;
      // fp32 weights: 4 consecutive cols of own row -> one plain dwordx4
      *(f32x4*)(wrow + c * kChunk + t * 16 + quad * 4) = (f32x4){w0, w1, w2, w3};
      // PV B-frag (W^T) for 16x16x16: B[k=quad*4+j][n=l15] = exactly this lane's w0..w3.
      const bf16x4 wfrag = {f2bf(w0), f2bf(w1), f2bf(w2), f2bf(w3)};
#pragma unroll
      for (int dt = 0; dt < 4; ++dt) {
        const int dd = dt * 16 + l15;
        const int pp = (8 * t + 2 * quad) ^ (((dd >> 3) & 7) << 2);
        const bf16x4 vfrag = *(const bf16x4*)&V[dd][2 * pp];   // A-frag: V^T[d][k=quad*4+j]
        acco[dt] = mfma16(vfrag, wfrag, acco[dt]);
      }
    }
    __builtin_amdgcn_s_setprio(0);
    block_sync_lds();
  }

  // ---- epilogue: lane holds O[q=own row][d = dt*16+quad*4+r] -> plain f32x4 stores ----
#pragma unroll
  for (int dt = 0; dt < 4; ++dt)
    *(f32x4*)(obase + (size_t)qrow * kD + dt * 16 + quad * 4) = acco[dt];
}

}  // namespace

extern "C" void kernel_launch(void* const* d_in, const int* in_sizes, int n_in,
                              void* d_out, int out_size, void* d_ws, size_t ws_size,
                              hipStream_t stream) {
  const float* q = (const float*)d_in[0];
  const float* k = (const float*)d_in[1];
  const float* v = (const float*)d_in[2];
  const unsigned int* mask = (const unsigned int*)d_in[3];
  float* out = (float*)d_out;  // fp32 output buffer (output ++ weights)
  attn_fused<<<dim3(kNB), dim3(256), 0, stream>>>(q, k, v, mask, out);
}

// Round 7
// 811.538 us; speedup vs baseline: 1.1153x; 1.1153x over previous
//
#include <hip/hip_runtime.h>
#include <hip/hip_bf16.h>

// ScaledDotProductAttention: B=2,H=16,S=2048,D=64 -> (output[B,H,S,D], weights[B,H,S,S]).
// Inputs float32, outputs FLOAT32. Two-pass flash-with-weights, bf16 MFMA, swapped operands.
// R9 = R8 + bit-packed cooperative mask staging:
//  - R8's per-lane mask loads were 64-line gathers consumed same-chunk (exposed latency,
//    TA serialization) -> regressed 379->449 despite fixing writes (705->548 MB) and
//    conflicts (35.6M->12.6M). Masks go back to LDS, but packed to BITS: 64x64 chunk =
//    512 B/buffer, double-buffered (1 KB total) -> fits with full K/V dbuf (37888 B,
//    4 blocks/CU). Coalesced uint4 loads, reg-staged 2 chunks ahead, ds_write_b16
//    (2-way, free), consumer ds_read_b64 per chunk (conflict-free, quad-broadcast).
//  - Kept from R8: PV B-frag straight from QK^T C-frag via mfma 16x16x16 (W never in
//    LDS), K/V double-buffer with 1 raw lgkmcnt-only barrier per chunk, plain stores.
//  - setprio(1) around MFMA clusters in BOTH passes.

namespace {

constexpr int kS = 2048;
constexpr int kD = 64;
constexpr int kBH = 32;            // B*H
constexpr int kTQW = 16;           // q rows per wave
constexpr int kNW = 4;             // waves per block
constexpr int kTQB = kTQW * kNW;   // 64 q rows per block
constexpr int kChunk = 64;         // k rows per chunk
constexpr int kNC = kS / kChunk;   // 32 chunks
constexpr int kNB = kBH * (kS / kTQB);           // 1024 blocks
constexpr size_t kWOff = (size_t)kBH * kS * kD;  // weights offset in d_out

typedef __attribute__((ext_vector_type(8))) short bf16x8;
typedef __attribute__((ext_vector_type(4))) short bf16x4;
typedef __attribute__((ext_vector_type(4))) float f32x4;

__device__ inline short f2bf(float f) {
  union { float f; unsigned u; } x; x.f = f;
  return (short)((x.u + 0x7fffu + ((x.u >> 16) & 1u)) >> 16);  // RNE
}

__device__ inline unsigned pk2bf(float a, float b) {
  return (unsigned)(unsigned short)f2bf(a) | ((unsigned)(unsigned short)f2bf(b) << 16);
}

__device__ inline bf16x8 cvt8(float4 a, float4 b, float scale) {
  bf16x8 f;
  f[0] = f2bf(a.x * scale); f[1] = f2bf(a.y * scale);
  f[2] = f2bf(a.z * scale); f[3] = f2bf(a.w * scale);
  f[4] = f2bf(b.x * scale); f[5] = f2bf(b.y * scale);
  f[6] = f2bf(b.z * scale); f[7] = f2bf(b.w * scale);
  return f;
}

__device__ inline f32x4 mfma32(bf16x8 a, bf16x8 b, f32x4 c) {
  return __builtin_amdgcn_mfma_f32_16x16x32_bf16(a, b, c, 0, 0, 0);
}

// 16x16x16 bf16 MFMA: builtin name differs across ROCm generations; chain with asm fallback.
__device__ inline f32x4 mfma16(bf16x4 a, bf16x4 b, f32x4 c) {
#if __has_builtin(__builtin_amdgcn_mfma_f32_16x16x16bf16_1k)
  return __builtin_amdgcn_mfma_f32_16x16x16bf16_1k(a, b, c, 0, 0, 0);
#elif __has_builtin(__builtin_amdgcn_mfma_f32_16x16x16_bf16)
  return __builtin_amdgcn_mfma_f32_16x16x16_bf16(a, b, c, 0, 0, 0);
#else
  f32x4 d = c;
  asm volatile("v_mfma_f32_16x16x16_bf16 %0, %1, %2, %0" : "+v"(d) : "v"(a), "v"(b));
  return d;
#endif
}

// Barrier that does NOT drain vmcnt: LDS writes made visible (lgkmcnt(0)); in-flight
// global loads/stores survive. "memory" clobbers pin compiler ordering.
__device__ inline void block_sync_lds() {
  asm volatile("s_waitcnt lgkmcnt(0)" ::: "memory");
  __builtin_amdgcn_s_barrier();
  asm volatile("" ::: "memory");
}

__global__ __launch_bounds__(256, 4) void attn_fused(
    const float* __restrict__ qg, const float* __restrict__ kg,
    const float* __restrict__ vg, const unsigned int* __restrict__ mg,
    float* __restrict__ outg) {
  // Shorts: K0,K1,V0,V1 [64][72] (36864 B) + Msk0,Msk1 bit-chunks (512 B each).
  // Total 37888 B -> 4 blocks/CU.
  __shared__ __align__(16) short SH[18944];
  short (*K0)[72] = (short(*)[72])(SH);
  short (*K1)[72] = (short(*)[72])(SH + 4608);
  short (*V0)[72] = (short(*)[72])(SH + 9216);
  short (*V1)[72] = (short(*)[72])(SH + 13824);
  unsigned short* Msk0 = (unsigned short*)(SH + 18432);  // [64 rows][4 shorts] bit rows
  unsigned short* Msk1 = (unsigned short*)(SH + 18688);

  const int tid  = threadIdx.x;
  const int wv   = tid >> 6;
  const int lane = tid & 63;
  const int l15  = lane & 15;
  const int quad = lane >> 4;

  // XCD-chunked bijective swizzle (1024 % 8 == 0): same-bh blocks share one XCD's L2.
  const int bid  = blockIdx.x;
  const int work = ((bid & 7) << 7) | (bid >> 3);
  const int qt   = work & 31;
  const int bh   = work >> 5;
  const int b    = bh >> 4;          // H = 16
  const int q0b  = qt * kTQB;

  // ---- mask encoding detection (uint8 | int32 | float32 | bf16), element test != 0 ----
  int allW32 = 1, allI32 = 1, allBF = 1;
#pragma unroll
  for (int i = 0; i < 64; ++i) {
    const unsigned u = mg[i];
    const unsigned lo = u & 0xFFFFu, hi = u >> 16;
    allW32 &= (int)(u == 0u || u == 0x3F800000u);
    allI32 &= (int)(u == 0u || u == 1u);
    allBF  &= (int)((lo == 0u || lo == 0x3F80u) && (hi == 0u || hi == 0x3F80u));
  }
  int msz;
  if (allI32)      msz = 4;
  else if (allW32) msz = 4;
  else if (allBF)  msz = 2;
  else             msz = 1;
  const unsigned char* mB = (const unsigned char*)mg + (size_t)b * kS * kS * msz;

  const float* qbase = qg + (size_t)bh * kS * kD;
  const float* kbase = kg + (size_t)bh * kS * kD;
  const float* vbase = vg + (size_t)bh * kS * kD;
  float* obase = outg + (size_t)bh * kS * kD;
  float* wbase = outg + kWOff + (size_t)bh * kS * kS;

  const int qrow = q0b + wv * kTQW + l15;   // row-per-lane (swapped layout)
  const int mrow = wv * kTQW + l15;

  // ---- Q fragments (B-operand of swapped QK^T), pre-scaled by 1/8, in registers ----
  bf16x8 aq[2];
#pragma unroll
  for (int dh = 0; dh < 2; ++dh) {
    const float* p = qbase + (size_t)qrow * kD + dh * 32 + quad * 8;
    aq[dh] = cvt8(*(const float4*)p, *(const float4*)(p + 4), 0.125f);
  }

  // ---- staging thread maps ----
  const int si  = tid >> 2;          // row 0..63
  const int sj  = (tid & 3) << 4;    // K col segment 0/16/32/48 (elements)
  const int sjw = tid & 3;           // mask 16-col group 0..3
  const int vd  = (tid & 7) << 3;    // V: d base
  const int vk  = (tid >> 3) << 1;   // V: even krel pair base
  float4 rk[4], rv[4];
  uint4 mrg[4];

  auto k_issue = [&](int c) {
    const float* p = kbase + (size_t)(c * kChunk + si) * kD + sj;
    rk[0] = *(const float4*)p;       rk[1] = *(const float4*)(p + 4);
    rk[2] = *(const float4*)(p + 8); rk[3] = *(const float4*)(p + 12);
  };
  auto k_write = [&](short (*Kdst)[72]) {
    *(bf16x8*)&Kdst[si][sj]     = cvt8(rk[0], rk[1], 1.0f);
    *(bf16x8*)&Kdst[si][sj + 8] = cvt8(rk[2], rk[3], 1.0f);
  };

  auto v_issue = [&](int c) {
    const float* p = vbase + (size_t)(c * kChunk + vk) * kD + vd;
    rv[0] = *(const float4*)p;        rv[1] = *(const float4*)(p + 4);
    rv[2] = *(const float4*)(p + kD); rv[3] = *(const float4*)(p + kD + 4);
  };
  // V^T: pair (vk,vk+1) packed per dword; pair index XOR-swizzled by d-group.
  auto v_write = [&](short (*Vdst)[72]) {
    const float* lo = (const float*)&rv[0];
    const float* hi = (const float*)&rv[2];
#pragma unroll
    for (int d = 0; d < 8; ++d) {
      const int dd = vd + d;
      const int ps = (vk >> 1) ^ (((dd >> 3) & 7) << 2);
      *(unsigned*)&Vdst[dd][2 * ps] = pk2bf(lo[d], hi[d]);
    }
  };

  // ---- mask: coalesced loads of 16 elements (row si, cols sjw*16..+15) -> 16 bits ----
  auto m_issue = [&](int c) {
    const size_t base = (size_t)(q0b + si) * kS + (size_t)(c * kChunk) + sjw * 16;
    if (msz == 4) {
      const uint4* p = (const uint4*)((const unsigned*)mB + base);
      mrg[0] = p[0]; mrg[1] = p[1]; mrg[2] = p[2]; mrg[3] = p[3];
    } else if (msz == 2) {
      const uint4* p = (const uint4*)((const unsigned short*)mB + base);
      mrg[0] = p[0]; mrg[1] = p[1];
    } else {
      mrg[0] = *(const uint4*)(mB + base);
    }
  };
  auto m_write = [&](unsigned short* Mdst) {
    unsigned bits = 0;
    if (msz == 4) {
#pragma unroll
      for (int g = 0; g < 4; ++g) {
        const uint4 e = mrg[g];
        bits |= (e.x ? 1u : 0u) << (4 * g + 0);
        bits |= (e.y ? 1u : 0u) << (4 * g + 1);
        bits |= (e.z ? 1u : 0u) << (4 * g + 2);
        bits |= (e.w ? 1u : 0u) << (4 * g + 3);
      }
    } else if (msz == 2) {
#pragma unroll
      for (int g = 0; g < 2; ++g) {
        const uint4 e = mrg[g];
        bits |= ((e.x & 0xFFFFu) ? 1u : 0u) << (8 * g + 0);
        bits |= ((e.x >> 16)     ? 1u : 0u) << (8 * g + 1);
        bits |= ((e.y & 0xFFFFu) ? 1u : 0u) << (8 * g + 2);
        bits |= ((e.y >> 16)     ? 1u : 0u) << (8 * g + 3);
        bits |= ((e.z & 0xFFFFu) ? 1u : 0u) << (8 * g + 4);
        bits |= ((e.z >> 16)     ? 1u : 0u) << (8 * g + 5);
        bits |= ((e.w & 0xFFFFu) ? 1u : 0u) << (8 * g + 6);
        bits |= ((e.w >> 16)     ? 1u : 0u) << (8 * g + 7);
      }
    } else {
      const uint4 e = mrg[0];
#pragma unroll
      for (int by = 0; by < 4; ++by) {
        bits |= (((e.x >> (8 * by)) & 0xFFu) ? 1u : 0u) << (0 + by);
        bits |= (((e.y >> (8 * by)) & 0xFFu) ? 1u : 0u) << (4 + by);
        bits |= (((e.z >> (8 * by)) & 0xFFu) ? 1u : 0u) << (8 + by);
        bits |= (((e.w >> (8 * by)) & 0xFFu) ? 1u : 0u) << (12 + by);
      }
    }
    Mdst[si * 4 + sjw] = (unsigned short)bits;
  };

  // ================= Pass A: l = sum_k exp(s); 1 barrier/chunk, dbuf =================
  float lsum = 0.f;
  k_issue(0); m_issue(0);
  k_write(K0); m_write(Msk0);
  k_issue(1); m_issue(1);
  block_sync_lds();
  for (int c = 0; c < kNC; ++c) {
    if (c + 1 < kNC) { k_write((c & 1) ? K0 : K1); m_write((c & 1) ? Msk0 : Msk1); }
    if (c + 2 < kNC) { k_issue(c + 2); m_issue(c + 2); }
    short (*K)[72] = (c & 1) ? K1 : K0;
    const unsigned short* M = (c & 1) ? Msk1 : Msk0;
    const unsigned long long mbits = *(const unsigned long long*)&M[mrow * 4];
    __builtin_amdgcn_s_setprio(1);
#pragma unroll
    for (int t = 0; t < 4; ++t) {
      bf16x8 f0 = *(const bf16x8*)&K[t * 16 + l15][quad * 8];
      bf16x8 f1 = *(const bf16x8*)&K[t * 16 + l15][32 + quad * 8];
      f32x4 acc = {0.f, 0.f, 0.f, 0.f};
      acc = mfma32(f0, aq[0], acc);
      acc = mfma32(f1, aq[1], acc);
      // S^T tile: lane holds S[q=own row][k = t*16 + quad*4 + r]
      const unsigned nib = (unsigned)(mbits >> (16 * t + 4 * quad)) & 0xFu;
#pragma unroll
      for (int r = 0; r < 4; ++r) {
        const float e = __expf(acc[r]);
        lsum += (nib & (1u << r)) ? 1.0f : e;   // masked -> exp(-1e-9) == 1.0f
      }
    }
    __builtin_amdgcn_s_setprio(0);
    block_sync_lds();
  }

  // reduce across the 4 quads holding this q row's column subsets
  lsum += __shfl_xor(lsum, 16);
  lsum += __shfl_xor(lsum, 32);
  const float inv = 1.0f / lsum;

  // ================= Pass B: weights (plain f32x4) + PV; 1 barrier/chunk ===============
  f32x4 acco[4];
#pragma unroll
  for (int d = 0; d < 4; ++d) acco[d] = (f32x4){0.f, 0.f, 0.f, 0.f};

  k_issue(0); v_issue(0); m_issue(0);
  k_write(K0); v_write(V0); m_write(Msk0);
  k_issue(1); v_issue(1); m_issue(1);
  block_sync_lds();
  float* const wrow = wbase + (size_t)qrow * kS;
  for (int c = 0; c < kNC; ++c) {
    if (c + 1 < kNC) {
      k_write((c & 1) ? K0 : K1); v_write((c & 1) ? V0 : V1);
      m_write((c & 1) ? Msk0 : Msk1);
    }
    if (c + 2 < kNC) { k_issue(c + 2); v_issue(c + 2); m_issue(c + 2); }
    short (*K)[72] = (c & 1) ? K1 : K0;
    short (*V)[72] = (c & 1) ? V1 : V0;
    const unsigned short* M = (c & 1) ? Msk1 : Msk0;
    const unsigned long long mbits = *(const unsigned long long*)&M[mrow * 4];
    __builtin_amdgcn_s_setprio(1);
#pragma unroll
    for (int t = 0; t < 4; ++t) {
      bf16x8 f0 = *(const bf16x8*)&K[t * 16 + l15][quad * 8];
      bf16x8 f1 = *(const bf16x8*)&K[t * 16 + l15][32 + quad * 8];
      f32x4 acc = {0.f, 0.f, 0.f, 0.f};
      acc = mfma32(f0, aq[0], acc);
      acc = mfma32(f1, aq[1], acc);
      const unsigned nib = (unsigned)(mbits >> (16 * t + 4 * quad)) & 0xFu;
      const float w0 = ((nib & 1u) ? 1.0f : __expf(acc[0])) * inv;
      const float w1 = ((nib & 2u) ? 1.0f : __expf(acc[1])) * inv;
      const float w2 = ((nib & 4u) ? 1.0f : __expf(acc[2])) * inv;
      const float w3 = ((nib & 8u) ? 1.0f : __expf(acc[3])) * inv;
      // fp32 weights: 4 consecutive cols of own row -> one plain dwordx4
      *(f32x4*)(wrow + c * kChunk + t * 16 + quad * 4) = (f32x4){w0, w1, w2, w3};
      // PV B-frag (W^T) for 16x16x16: B[k=quad*4+j][n=l15] = exactly this lane's w0..w3.
      const bf16x4 wfrag = {f2bf(w0), f2bf(w1), f2bf(w2), f2bf(w3)};
#pragma unroll
      for (int dt = 0; dt < 4; ++dt) {
        const int dd = dt * 16 + l15;
        const int pp = (8 * t + 2 * quad) ^ (((dd >> 3) & 7) << 2);
        const bf16x4 vfrag = *(const bf16x4*)&V[dd][2 * pp];   // A-frag: V^T[d][k=quad*4+j]
        acco[dt] = mfma16(vfrag, wfrag, acco[dt]);
      }
    }
    __builtin_amdgcn_s_setprio(0);
    block_sync_lds();
  }

  // ---- epilogue: lane holds O[q=own row][d = dt*16+quad*4+r] -> plain f32x4 stores ----
#pragma unroll
  for (int dt = 0; dt < 4; ++dt)
    *(f32x4*)(obase + (size_t)qrow * kD + dt * 16 + quad * 4) = acco[dt];
}

}  // namespace

extern "C" void kernel_launch(void* const* d_in, const int* in_sizes, int n_in,
                              void* d_out, int out_size, void* d_ws, size_t ws_size,
                              hipStream_t stream) {
  const float* q = (const float*)d_in[0];
  const float* k = (const float*)d_in[1];
  const float* v = (const float*)d_in[2];
  const unsigned int* mask = (const unsigned int*)d_in[3];
  float* out = (float*)d_out;  // fp32 output buffer (output ++ weights)
  attn_fused<<<dim3(kNB), dim3(256), 0, stream>>>(q, k, v, mask, out);
}